// Round 1
// baseline (495.092 us; speedup 1.0000x reference)
//
#include <hip/hip_runtime.h>
#include <cstdint>
#include <cstddef>

typedef __bf16 bf16_t;
typedef __attribute__((ext_vector_type(4))) __bf16 bf16x4_t;
typedef __attribute__((ext_vector_type(8))) __bf16 bf16x8_t;
typedef __attribute__((ext_vector_type(4))) float f32x4_t;

#define T_TOK   4096
#define IN_DIM  4096
#define OUT_DIM 4096
#define N1      4352   // OUT_DIM + 256 svh rows (= 34 * 128 exactly)
#define K2      288    // 256 hk cols + 8 bias cols + 24 zero pad (9 * 32)
#define KSPLIT  8

__device__ __forceinline__ void gload_lds16(const bf16_t* g, bf16_t* l) {
  __builtin_amdgcn_global_load_lds(
      (__attribute__((address_space(1))) void*)(g),
      (__attribute__((address_space(3))) void*)(l), 16, 0, 0);
}

// ---------------- fp32 -> bf16 cast (memory-bound, float4/8B-vectorized) ----
__global__ __launch_bounds__(256) void cast_kernel(const float* __restrict__ src,
                                                   bf16_t* __restrict__ dst) {
  size_t i = ((size_t)blockIdx.x * 256 + threadIdx.x) * 4;
  float4 v = *(const float4*)(src + i);
  bf16x4_t o;
  o[0] = (__bf16)v.x; o[1] = (__bf16)v.y; o[2] = (__bf16)v.z; o[3] = (__bf16)v.w;
  *(bf16x4_t*)(dst + i) = o;
}

// ---------------- fp32 gate matmul, split-K partials ------------------------
// grid (T/64, KSPLIT), block 256. partial[ks][t][r] = sum_{k in split} x*g
__global__ __launch_bounds__(256) void gate_partial(const float* __restrict__ x,
                                                    const float* __restrict__ g,
                                                    float* __restrict__ part) {
  __shared__ __align__(16) float Xs[64 * 68];  // [kk][t], pad 68 keeps 16B align
  __shared__ __align__(16) float Gs[64 * 68];  // [kk][r]
  const int tid = threadIdx.x;
  const int tbase = blockIdx.x * 64;
  const int kbase = blockIdx.y * (IN_DIM / KSPLIT);  // 512-wide K split
  const int tg = tid & 15;   // token group: tokens tg*4..+3
  const int rg = tid >> 4;   // r group: r = rg*4..+3
  float acc[4][4] = {{0.f}};

  for (int cc = 0; cc < (IN_DIM / KSPLIT) / 64; ++cc) {
    const int kc = kbase + cc * 64;
    __syncthreads();
#pragma unroll
    for (int j = 0; j < 4; ++j) {
      const int f = tid * 16 + j * 4;   // 0..4095 over the 64x64 tile
      const int tt = f >> 6, k4 = f & 63;
      float4 xv = *(const float4*)&x[(size_t)(tbase + tt) * IN_DIM + kc + k4];
      Xs[(k4 + 0) * 68 + tt] = xv.x; Xs[(k4 + 1) * 68 + tt] = xv.y;
      Xs[(k4 + 2) * 68 + tt] = xv.z; Xs[(k4 + 3) * 68 + tt] = xv.w;
      float4 gv = *(const float4*)&g[(size_t)tt * IN_DIM + kc + k4];
      Gs[(k4 + 0) * 68 + tt] = gv.x; Gs[(k4 + 1) * 68 + tt] = gv.y;
      Gs[(k4 + 2) * 68 + tt] = gv.z; Gs[(k4 + 3) * 68 + tt] = gv.w;
    }
    __syncthreads();
#pragma unroll 4
    for (int kk = 0; kk < 64; ++kk) {
      float4 xv = *(const float4*)&Xs[kk * 68 + tg * 4];
      float4 gv = *(const float4*)&Gs[kk * 68 + rg * 4];
      float xa[4] = {xv.x, xv.y, xv.z, xv.w};
      float ga[4] = {gv.x, gv.y, gv.z, gv.w};
#pragma unroll
      for (int i = 0; i < 4; ++i)
#pragma unroll
        for (int j = 0; j < 4; ++j) acc[i][j] = fmaf(xa[i], ga[j], acc[i][j]);
    }
  }
#pragma unroll
  for (int i = 0; i < 4; ++i) {
    float4 o4 = make_float4(acc[i][0], acc[i][1], acc[i][2], acc[i][3]);
    *(float4*)&part[((size_t)blockIdx.y * T_TOK + tbase + tg * 4 + i) * 64 + rg * 4] = o4;
  }
}

// ---------------- router: L2-norm logits, softmax, top-2, dense weights -----
__global__ __launch_bounds__(64) void router_kernel(const float* __restrict__ part,
                                                    float* __restrict__ wts) {
  const int t = blockIdx.x * 64 + threadIdx.x;
  float rl2[8];
#pragma unroll
  for (int e = 0; e < 8; ++e) rl2[e] = 0.f;
#pragma unroll
  for (int r4 = 0; r4 < 16; ++r4) {
    float4 s = make_float4(0.f, 0.f, 0.f, 0.f);
    for (int ks = 0; ks < KSPLIT; ++ks) {
      float4 p = *(const float4*)&part[((size_t)ks * T_TOK + t) * 64 + r4 * 4];
      s.x += p.x; s.y += p.y; s.z += p.z; s.w += p.w;
    }
    rl2[r4 >> 1] += s.x * s.x + s.y * s.y + s.z * s.z + s.w * s.w;
  }
  float rl[8];
#pragma unroll
  for (int e = 0; e < 8; ++e) rl[e] = sqrtf(rl2[e]);
  // top-2 with first-index tie-break (matches lax.top_k)
  int e1 = 0; float v1 = rl[0];
#pragma unroll
  for (int e = 1; e < 8; ++e) if (rl[e] > v1) { v1 = rl[e]; e1 = e; }
  int e2 = -1; float v2 = -1e30f;
#pragma unroll
  for (int e = 0; e < 8; ++e) if (e != e1 && rl[e] > v2) { v2 = rl[e]; e2 = e; }
  // normalized top-2 softmax == pairwise softmax of the two logits
  float w1 = 1.f / (1.f + expf(v2 - v1));
  float o[8];
#pragma unroll
  for (int e = 0; e < 8; ++e) o[e] = 0.f;
  o[e1] = w1; o[e2] = 1.f - w1;
  *(float4*)&wts[(size_t)t * 8 + 0] = make_float4(o[0], o[1], o[2], o[3]);
  *(float4*)&wts[(size_t)t * 8 + 4] = make_float4(o[4], o[5], o[6], o[7]);
}

// ---------------- A2 = [hk * w_e | w_e | 0pad] in bf16 ----------------------
__global__ __launch_bounds__(256) void build_a2(const float* __restrict__ hk,
                                                const float* __restrict__ wts,
                                                bf16_t* __restrict__ A2) {
  const int t = blockIdx.x;
  for (int c = threadIdx.x; c < K2; c += 256) {
    float v;
    if (c < 256)      v = hk[(size_t)t * 256 + c] * wts[(size_t)t * 8 + (c >> 5)];
    else if (c < 264) v = wts[(size_t)t * 8 + (c - 256)];
    else              v = 0.f;
    A2[(size_t)t * K2 + c] = (__bf16)v;
  }
}

// ---------------- B2t[o][c] = u[e][o][k] (c=e*32+k) | bias[e][o] | 0 --------
__global__ __launch_bounds__(256) void build_b2t(const float* __restrict__ u,
                                                 const float* __restrict__ eb,
                                                 bf16_t* __restrict__ B2t) {
  const int o = blockIdx.x;
  for (int c = threadIdx.x; c < K2; c += 256) {
    float v;
    if (c < 256)      v = u[((size_t)(c >> 5) * OUT_DIM + o) * 32 + (c & 31)];
    else if (c < 264) v = eb[(size_t)(c - 256) * OUT_DIM + o];
    else              v = 0.f;
    B2t[(size_t)o * K2 + c] = (__bf16)v;
  }
}

// ---------------- m97-style bf16 MFMA GEMM: C[m,n] = sum_k A[m,k]*Bt[n,k] ---
// 128x128 tile, BK=32, 256 thr = 4 waves (2x2 of 64x64), global_load_lds x16.
// MODE 0: n<4096 -> out[m][n]=acc+bias[n]; else hk[m][n-4096]=acc   (gemm1)
// MODE 1: out[m][n] += acc                                          (gemm2)
template <int MODE>
__global__ __launch_bounds__(256) void gemm_bt(const bf16_t* __restrict__ A,
                                               const bf16_t* __restrict__ Bt,
                                               int K, int lda, int ldb,
                                               float* __restrict__ out,
                                               const float* __restrict__ bias,
                                               float* __restrict__ hk) {
  __shared__ __align__(16) bf16_t As[128 * 32];
  __shared__ __align__(16) bf16_t Bs[128 * 32];
  const int tid = threadIdx.x;
  const int wave = tid >> 6, lane = tid & 63;
  const int mBase = blockIdx.y * 128, nBase = blockIdx.x * 128;
  const int wm = wave >> 1, wn = wave & 1;
  const int lr = lane & 15, lk = (lane >> 4) * 8;
  const int arow = lane >> 2, acol = (lane & 3) * 8;

  f32x4_t acc[4][4];
#pragma unroll
  for (int i = 0; i < 4; ++i)
#pragma unroll
    for (int j = 0; j < 4; ++j) {
      f32x4_t z = {0.f, 0.f, 0.f, 0.f};
      acc[i][j] = z;
    }

  const bf16_t* gA = A + (size_t)(mBase + wave * 32 + arow) * lda + acol;
  const bf16_t* gB = Bt + (size_t)(nBase + wave * 32 + arow) * ldb + acol;
  bf16_t* lA = &As[(wave * 32) * 32];
  bf16_t* lB = &Bs[(wave * 32) * 32];

  for (int k0 = 0; k0 < K; k0 += 32) {
    gload_lds16(gA + k0, lA);
    gload_lds16(gA + k0 + (size_t)16 * lda, lA + 16 * 32);
    gload_lds16(gB + k0, lB);
    gload_lds16(gB + k0 + (size_t)16 * ldb, lB + 16 * 32);
    __syncthreads();   // drains vmcnt (global_load_lds) + orders LDS
    bf16x8_t a[4], b[4];
#pragma unroll
    for (int mi = 0; mi < 4; ++mi)
      a[mi] = *(const bf16x8_t*)&As[(wm * 64 + mi * 16 + lr) * 32 + lk];
#pragma unroll
    for (int ni = 0; ni < 4; ++ni)
      b[ni] = *(const bf16x8_t*)&Bs[(wn * 64 + ni * 16 + lr) * 32 + lk];
#pragma unroll
    for (int mi = 0; mi < 4; ++mi)
#pragma unroll
      for (int ni = 0; ni < 4; ++ni)
        acc[mi][ni] = __builtin_amdgcn_mfma_f32_16x16x32_bf16(a[mi], b[ni], acc[mi][ni], 0, 0, 0);
    __syncthreads();   // protect LDS before next staging
  }

  const int row0 = (lane >> 4) * 4;  // C/D: col = lane&15, row = (lane>>4)*4 + r
#pragma unroll
  for (int mi = 0; mi < 4; ++mi) {
    const int m = mBase + wm * 64 + mi * 16 + row0;
#pragma unroll
    for (int ni = 0; ni < 4; ++ni) {
      const int n = nBase + wn * 64 + ni * 16 + lr;
      f32x4_t v = acc[mi][ni];
      if (MODE == 0) {
        if (n < OUT_DIM) {
          const float bn = bias[n];
#pragma unroll
          for (int r = 0; r < 4; ++r) out[(size_t)(m + r) * OUT_DIM + n] = v[r] + bn;
        } else {
#pragma unroll
          for (int r = 0; r < 4; ++r) hk[(size_t)(m + r) * 256 + (n - OUT_DIM)] = v[r];
        }
      } else {
#pragma unroll
        for (int r = 0; r < 4; ++r) out[(size_t)(m + r) * OUT_DIM + n] += v[r];
      }
    }
  }
}

extern "C" void kernel_launch(void* const* d_in, const int* in_sizes, int n_in,
                              void* d_out, int out_size, void* d_ws, size_t ws_size,
                              hipStream_t stream) {
  const float* x   = (const float*)d_in[0];  // [T, IN]
  const float* gw  = (const float*)d_in[1];  // [64, IN]
  const float* sw  = (const float*)d_in[2];  // [OUT, IN]
  const float* sb  = (const float*)d_in[3];  // [OUT]
  const float* u   = (const float*)d_in[4];  // [E, OUT, 32]
  const float* svh = (const float*)d_in[5];  // [E, 32, IN] == [256, IN]
  const float* eb  = (const float*)d_in[6];  // [E, OUT]
  float* out = (float*)d_out;

  char* ws = (char*)d_ws;
  size_t off = 0;
  auto carve = [&](size_t bytes) {
    void* p = ws + off;
    off = (off + bytes + 255) & ~(size_t)255;
    return p;
  };
  bf16_t* Xbf  = (bf16_t*)carve((size_t)T_TOK * IN_DIM * 2);
  bf16_t* Wbf  = (bf16_t*)carve((size_t)N1 * IN_DIM * 2);
  float*  hk   = (float*)carve((size_t)T_TOK * 256 * 4);
  float*  part = (float*)carve((size_t)KSPLIT * T_TOK * 64 * 4);
  float*  wts  = (float*)carve((size_t)T_TOK * 8 * 4);
  bf16_t* A2   = (bf16_t*)carve((size_t)T_TOK * K2 * 2);
  bf16_t* B2t  = (bf16_t*)carve((size_t)OUT_DIM * K2 * 2);
  (void)ws_size; (void)in_sizes; (void)n_in; (void)out_size;

  // casts: x -> Xbf ; [shared_w ; svh] -> Wbf (N1 = 4352 rows)
  cast_kernel<<<(T_TOK * IN_DIM) / 1024, 256, 0, stream>>>(x, Xbf);
  cast_kernel<<<(OUT_DIM * IN_DIM) / 1024, 256, 0, stream>>>(sw, Wbf);
  cast_kernel<<<(256 * IN_DIM) / 1024, 256, 0, stream>>>(svh, Wbf + (size_t)OUT_DIM * IN_DIM);

  // fp32 gate (router precision!) + topk weights
  gate_partial<<<dim3(T_TOK / 64, KSPLIT), 256, 0, stream>>>(x, gw, part);
  router_kernel<<<T_TOK / 64, 64, 0, stream>>>(part, wts);

  // expert second-stage weight matrix (independent of gemm1)
  build_b2t<<<OUT_DIM, 256, 0, stream>>>(u, eb, B2t);

  // GEMM1: [T,4096] x [4352,4096]^T -> pretrained(+bias) into d_out, hk into ws
  gemm_bt<0><<<dim3(N1 / 128, T_TOK / 128), 256, 0, stream>>>(
      Xbf, Wbf, IN_DIM, IN_DIM, IN_DIM, out, sb, hk);

  // A2 = [hk*w | w | 0], then GEMM2 accumulates expert output into d_out
  build_a2<<<T_TOK, 256, 0, stream>>>(hk, wts, A2);
  gemm_bt<1><<<dim3(OUT_DIM / 128, T_TOK / 128), 256, 0, stream>>>(
      A2, B2t, K2, K2, K2, out, nullptr, nullptr);
}